// Round 3
// baseline (148.394 us; speedup 1.0000x reference)
//
#include <hip/hip_runtime.h>
#include <stdint.h>

#define B 1024
#define F 256
#define D 64

typedef __attribute__((ext_vector_type(8))) short short8;
typedef __attribute__((ext_vector_type(4))) float f32x4;

__device__ __forceinline__ short f2bf(float f) {
    unsigned u = __builtin_bit_cast(unsigned, f);
    u += 0x7fff + ((u >> 16) & 1);   // RNE
    return (short)(u >> 16);
}
__device__ __forceinline__ float bf2f(short s) {
    unsigned u = ((unsigned)(unsigned short)s) << 16;
    return __builtin_bit_cast(float, u);
}
// pack two f32 -> two bf16 (round-half-up), 3 VALU
__device__ __forceinline__ unsigned pk_bf16(float a, float b) {
    unsigned ua = __builtin_bit_cast(unsigned, a) + 0x8000u;
    unsigned ub = __builtin_bit_cast(unsigned, b) + 0x8000u;
    return __builtin_amdgcn_perm(ub, ua, 0x07060302u);  // [bf16(a) | bf16(b)<<16]
}

// ---------------------------------------------------------------------------
// Workspace (floats/shorts, 16B-aligned sections):
//   trans : 2*F*D f32
//   qkv   : 3*F*D f32
//   g     : B*F  f32      g[b,f] = s0*s2
//   At    : [F/32][F][32] bf16   (gate*cross, K-tiled)
//   q2K   : [F/32][D][32] bf16   (qkv2^T, K-tiled)
//   s1b   : B*F  bf16
// ---------------------------------------------------------------------------

// Kernel A: trans/qkv = indicator @ W
__global__ void precompute_trans(const float* __restrict__ indicator,
                                 const float* __restrict__ W_qk,
                                 const float* __restrict__ W_qkv,
                                 float* __restrict__ trans,
                                 float* __restrict__ qkv) {
    int idx = blockIdx.x * blockDim.x + threadIdx.x;   // 0 .. 5*F*D
    int n   = idx / (F * D);
    int rem = idx - n * (F * D);
    int f   = rem / D;
    int e   = rem - f * D;
    const float* W = (n < 2) ? (W_qk + n * D * D) : (W_qkv + (n - 2) * D * D);
    const float* ind = indicator + f * D;
    float acc = 0.f;
#pragma unroll 8
    for (int d = 0; d < D; ++d) acc += ind[d] * W[d * D + e];
    if (n < 2) trans[n * F * D + f * D + e] = acc;
    else       qkv[(n - 2) * F * D + f * D + e] = acc;
}

// Kernel B: At[(j>>5)][i][j&31] = bf16( gate(i,j) ? qkv1[i].qkv0[j] : 0 )
//           q2K[(i>>5)][j][i&31] = bf16( qkv2[i][j] )  for j < 64
__global__ __launch_bounds__(256) void compute_Mt(const float* __restrict__ trans,
                                                  const float* __restrict__ qkv,
                                                  short* __restrict__ At,
                                                  short* __restrict__ q2K) {
    int j = blockIdx.x;    // F blocks
    int i = threadIdx.x;   // F threads
    const float4* t0 = (const float4*)(trans + i * D);
    const float4* t1 = (const float4*)(trans + F * D + j * D);
    const float4* q1 = (const float4*)(qkv + F * D + i * D);
    const float4* q0 = (const float4*)(qkv + j * D);
    float d0 = 0.f, d1 = 0.f;
#pragma unroll
    for (int k = 0; k < D / 4; ++k) {
        float4 a = t0[k], b = t1[k], c = q1[k], e = q0[k];
        d0 += a.x * b.x + a.y * b.y + a.z * b.z + a.w * b.w;
        d1 += c.x * e.x + c.y * e.y + c.z * e.z + c.w * e.w;
    }
    float v = (d0 > 0.f) ? d1 : 0.f;
    At[((j >> 5) * F + i) * 32 + (j & 31)] = f2bf(v);
    if (j < D) q2K[((i >> 5) * D + j) * 32 + (i & 31)] = f2bf(qkv[2 * F * D + i * D + j]);
}

// Kernel C: per row (b,f): g = (feat.qkv0)*(feat.qkv2), s1b = bf16(feat.qkv1)
// 16 lanes per row, coalesced float4 loads, shfl_xor reduce.
__global__ __launch_bounds__(256) void compute_s(const float* __restrict__ feature,
                                                 const float* __restrict__ qkv,
                                                 float* __restrict__ g,
                                                 short* __restrict__ s1b) {
    int gid = blockIdx.x * 256 + threadIdx.x;
    int row = gid >> 4;          // b*F + f
    int l   = gid & 15;
    int f   = row & (F - 1);
    float4 fv = ((const float4*)(feature + (size_t)row * D))[l];
    float4 q0 = ((const float4*)(qkv + f * D))[l];
    float4 q1 = ((const float4*)(qkv + F * D + f * D))[l];
    float4 q2 = ((const float4*)(qkv + 2 * F * D + f * D))[l];
    float p0 = fv.x * q0.x + fv.y * q0.y + fv.z * q0.z + fv.w * q0.w;
    float p1 = fv.x * q1.x + fv.y * q1.y + fv.z * q1.z + fv.w * q1.w;
    float p2 = fv.x * q2.x + fv.y * q2.y + fv.z * q2.z + fv.w * q2.w;
#pragma unroll
    for (int m = 1; m < 16; m <<= 1) {
        p0 += __shfl_xor(p0, m, 64);
        p1 += __shfl_xor(p1, m, 64);
        p2 += __shfl_xor(p2, m, 64);
    }
    if (l == 0) {
        g[row]   = p0 * p2;
        s1b[row] = f2bf(p1);
    }
}

// Kernel D (MFMA, zero LDS, zero barriers):
// block (bp, ih): C[128 i][128 n] = At_rows[i0..i0+128] @ B, n = wc*64 + d,
//   B[n][j] = s1[b0+wc][j] * qkv2[j][d]   (computed in registers per fragment)
// out[b, i, d] = g[b,i] * C
__global__ __launch_bounds__(256) void main_mfma(const short* __restrict__ At,
                                                 const short* __restrict__ q2K,
                                                 const short* __restrict__ s1b,
                                                 const float* __restrict__ g,
                                                 float* __restrict__ out) {
    int blk = blockIdx.x;
    int ih  = blk & 1;        // i-half
    int bp  = blk >> 1;       // batch pair
    int b0  = bp * 2;
    int i0  = ih * 128;

    int tid  = threadIdx.x;
    int wave = tid >> 6;
    int lane = tid & 63;
    int wr   = wave >> 1, wc = wave & 1;   // wave's 64x64 quadrant (M=i, N=n)
    int l16  = lane & 15;
    int lq   = lane >> 4;                  // 0..3
    int b    = b0 + wc;

    f32x4 acc[4][4];
#pragma unroll
    for (int mt = 0; mt < 4; ++mt)
#pragma unroll
        for (int nt = 0; nt < 4; ++nt) acc[mt][nt] = (f32x4){0.f, 0.f, 0.f, 0.f};

    for (int jt = 0; jt < F / 32; ++jt) {
        int kq = lq * 8;                   // this lane's k-offset within the 32-tile
        // s1 fragment (broadcast across l16): 8 bf16 -> f32
        short8 sv = *(const short8*)(s1b + b * F + jt * 32 + kq);
        float sf[8];
#pragma unroll
        for (int e = 0; e < 8; ++e) sf[e] = bf2f(sv[e]);

        // A fragments: 16B per lane, quarter-wave contiguous (L2-resident)
        short8 af[4];
#pragma unroll
        for (int mt = 0; mt < 4; ++mt) {
            int i = i0 + wr * 64 + mt * 16 + l16;
            af[mt] = *(const short8*)(At + (jt * F + i) * 32 + kq);
        }
        // B fragments: load q2K row d, scale by s1, pack to bf16 in registers
        short8 bf[4];
#pragma unroll
        for (int nt = 0; nt < 4; ++nt) {
            int d = nt * 16 + l16;
            short8 qv = *(const short8*)(q2K + (jt * D + d) * 32 + kq);
            int4 packed;
            packed.x = pk_bf16(bf2f(qv[0]) * sf[0], bf2f(qv[1]) * sf[1]);
            packed.y = pk_bf16(bf2f(qv[2]) * sf[2], bf2f(qv[3]) * sf[3]);
            packed.z = pk_bf16(bf2f(qv[4]) * sf[4], bf2f(qv[5]) * sf[5]);
            packed.w = pk_bf16(bf2f(qv[6]) * sf[6], bf2f(qv[7]) * sf[7]);
            bf[nt] = __builtin_bit_cast(short8, packed);
        }
#pragma unroll
        for (int mt = 0; mt < 4; ++mt)
#pragma unroll
            for (int nt = 0; nt < 4; ++nt)
                acc[mt][nt] = __builtin_amdgcn_mfma_f32_16x16x32_bf16(
                    af[mt], bf[nt], acc[mt][nt], 0, 0, 0);
    }

    // epilogue: out[b, i, d] = g * acc   (row = quad*4+reg -> i, col = l16 -> d)
#pragma unroll
    for (int mt = 0; mt < 4; ++mt) {
#pragma unroll
        for (int r = 0; r < 4; ++r) {
            int i_loc = wr * 64 + mt * 16 + lq * 4 + r;
            float gg = g[b * F + i0 + i_loc];
            float* orow = out + ((size_t)(b * F + i0 + i_loc)) * D;
#pragma unroll
            for (int nt = 0; nt < 4; ++nt)
                orow[nt * 16 + l16] = gg * acc[mt][nt][r];
        }
    }
}

extern "C" void kernel_launch(void* const* d_in, const int* in_sizes, int n_in,
                              void* d_out, int out_size, void* d_ws, size_t ws_size,
                              hipStream_t stream) {
    const float* feature   = (const float*)d_in[0];
    const float* indicator = (const float*)d_in[1];
    const float* W_qk      = (const float*)d_in[2];
    const float* W_qkv     = (const float*)d_in[3];
    float* out = (float*)d_out;

    float* ws    = (float*)d_ws;
    float* trans = ws;                    // 2*F*D f32
    float* qkv   = trans + 2 * F * D;     // 3*F*D f32
    float* g     = qkv + 3 * F * D;       // B*F f32
    short* At    = (short*)(g + B * F);   // F*F bf16 (K-tiled)
    short* q2K   = At + F * F;            // (F/32)*D*32 bf16 (K-tiled)
    short* s1b   = q2K + (F / 32) * D * 32; // B*F bf16

    hipLaunchKernelGGL(precompute_trans, dim3((5 * F * D) / 256), dim3(256), 0,
                       stream, indicator, W_qk, W_qkv, trans, qkv);
    hipLaunchKernelGGL(compute_Mt, dim3(F), dim3(F), 0, stream, trans, qkv, At, q2K);
    hipLaunchKernelGGL(compute_s, dim3(B * F * 16 / 256), dim3(256), 0, stream,
                       feature, qkv, g, s1b);
    hipLaunchKernelGGL(main_mfma, dim3(B), dim3(256), 0, stream, At, q2K,
                       s1b, g, out);
}

// Round 4
// 143.116 us; speedup vs baseline: 1.0369x; 1.0369x over previous
//
#include <hip/hip_runtime.h>
#include <stdint.h>

#define B 1024
#define F 256
#define D 64

typedef __attribute__((ext_vector_type(8))) short short8;
typedef __attribute__((ext_vector_type(4))) float f32x4;

__device__ __forceinline__ short f2bf(float f) {
    unsigned u = __builtin_bit_cast(unsigned, f);
    u += 0x7fff + ((u >> 16) & 1);   // RNE
    return (short)(u >> 16);
}
__device__ __forceinline__ float bf2f(short s) {
    unsigned u = ((unsigned)(unsigned short)s) << 16;
    return __builtin_bit_cast(float, u);
}
// pack two f32 -> two bf16 (round-half-up), 3 VALU
__device__ __forceinline__ unsigned pk_bf16(float a, float b) {
    unsigned ua = __builtin_bit_cast(unsigned, a) + 0x8000u;
    unsigned ub = __builtin_bit_cast(unsigned, b) + 0x8000u;
    return __builtin_amdgcn_perm(ub, ua, 0x07060302u);  // [bf16(a) | bf16(b)<<16]
}

// ---------------------------------------------------------------------------
// Workspace:
//   trans : 2*F*D f32
//   qkv   : 3*F*D f32
//   At    : [F/32][F][32] bf16   (gate*cross, K-tiled)
//   q2K   : [F/32][D][32] bf16   (qkv2^T, K-tiled)
// ---------------------------------------------------------------------------

// Kernel A: trans/qkv = indicator @ W
__global__ void precompute_trans(const float* __restrict__ indicator,
                                 const float* __restrict__ W_qk,
                                 const float* __restrict__ W_qkv,
                                 float* __restrict__ trans,
                                 float* __restrict__ qkv) {
    int idx = blockIdx.x * blockDim.x + threadIdx.x;   // 0 .. 5*F*D
    int n   = idx / (F * D);
    int rem = idx - n * (F * D);
    int f   = rem / D;
    int e   = rem - f * D;
    const float* W = (n < 2) ? (W_qk + n * D * D) : (W_qkv + (n - 2) * D * D);
    const float* ind = indicator + f * D;
    float acc = 0.f;
#pragma unroll 8
    for (int d = 0; d < D; ++d) acc += ind[d] * W[d * D + e];
    if (n < 2) trans[n * F * D + f * D + e] = acc;
    else       qkv[(n - 2) * F * D + f * D + e] = acc;
}

// Kernel B: At[(j>>5)][i][j&31] = bf16( gate(i,j) ? qkv1[i].qkv0[j] : 0 )
//           q2K[(i>>5)][j][i&31] = bf16( qkv2[i][j] )  for j < 64
__global__ __launch_bounds__(256) void compute_Mt(const float* __restrict__ trans,
                                                  const float* __restrict__ qkv,
                                                  short* __restrict__ At,
                                                  short* __restrict__ q2K) {
    int j = blockIdx.x;    // F blocks
    int i = threadIdx.x;   // F threads
    const float4* t0 = (const float4*)(trans + i * D);
    const float4* t1 = (const float4*)(trans + F * D + j * D);
    const float4* q1 = (const float4*)(qkv + F * D + i * D);
    const float4* q0 = (const float4*)(qkv + j * D);
    float d0 = 0.f, d1 = 0.f;
#pragma unroll
    for (int k = 0; k < D / 4; ++k) {
        float4 a = t0[k], b = t1[k], c = q1[k], e = q0[k];
        d0 += a.x * b.x + a.y * b.y + a.z * b.z + a.w * b.w;
        d1 += c.x * e.x + c.y * e.y + c.z * e.z + c.w * e.w;
    }
    float v = (d0 > 0.f) ? d1 : 0.f;
    At[((j >> 5) * F + i) * 32 + (j & 31)] = f2bf(v);
    if (j < D) q2K[((i >> 5) * D + j) * 32 + (i & 31)] = f2bf(qkv[2 * F * D + i * D + j]);
}

// Fused kernel: one block per batch pair (b0, b0+1).
// Phase 1: s[n,b,f] = feature[b,f,:].qkv[n,f,:] -> gL = s0*s2 (f32), s1L (bf16) in LDS.
// Phase 2: per wave (wr,wc): C[128 i][64 d] for batch b0+wc, i-half wr.
//   B[j][d] = s1[b][j]*qkv2[j][d] built in registers from q2K + s1L.
//   out[b,i,d] = gL[b][i] * C.
__global__ __launch_bounds__(256, 2) void fused_main(const float* __restrict__ feature,
                                                     const float* __restrict__ qkv,
                                                     const short* __restrict__ At,
                                                     const short* __restrict__ q2K,
                                                     float* __restrict__ out) {
    int bp = blockIdx.x;
    int b0 = bp * 2;
    int tid = threadIdx.x;

    __shared__ __align__(16) short s1L[2 * F];
    __shared__ float gL[2 * F];

    // ---- Phase 1: compute s for both batches, 16 lanes per f-row ----
    {
        int rg = tid >> 4;     // 16 f-rows in flight
        int l  = tid & 15;
#pragma unroll 4
        for (int p = 0; p < 16; ++p) {
            int f = p * 16 + rg;
            float4 fv0 = ((const float4*)(feature + ((size_t)(b0 * F + f)) * D))[l];
            float4 fv1 = ((const float4*)(feature + ((size_t)((b0 + 1) * F + f)) * D))[l];
            float4 q0 = ((const float4*)(qkv + f * D))[l];
            float4 q1 = ((const float4*)(qkv + F * D + f * D))[l];
            float4 q2 = ((const float4*)(qkv + 2 * F * D + f * D))[l];
            float a00 = fv0.x * q0.x + fv0.y * q0.y + fv0.z * q0.z + fv0.w * q0.w;
            float a01 = fv0.x * q1.x + fv0.y * q1.y + fv0.z * q1.z + fv0.w * q1.w;
            float a02 = fv0.x * q2.x + fv0.y * q2.y + fv0.z * q2.z + fv0.w * q2.w;
            float a10 = fv1.x * q0.x + fv1.y * q0.y + fv1.z * q0.z + fv1.w * q0.w;
            float a11 = fv1.x * q1.x + fv1.y * q1.y + fv1.z * q1.z + fv1.w * q1.w;
            float a12 = fv1.x * q2.x + fv1.y * q2.y + fv1.z * q2.z + fv1.w * q2.w;
#pragma unroll
            for (int m = 1; m < 16; m <<= 1) {
                a00 += __shfl_xor(a00, m, 64);
                a01 += __shfl_xor(a01, m, 64);
                a02 += __shfl_xor(a02, m, 64);
                a10 += __shfl_xor(a10, m, 64);
                a11 += __shfl_xor(a11, m, 64);
                a12 += __shfl_xor(a12, m, 64);
            }
            if (l == 0) {
                gL[f]       = a00 * a02;
                gL[F + f]   = a10 * a12;
                s1L[f]      = f2bf(a01);
                s1L[F + f]  = f2bf(a11);
            }
        }
    }
    __syncthreads();

    // ---- Phase 2: MFMA GEMM, no further barriers ----
    int wave = tid >> 6;
    int lane = tid & 63;
    int wr   = wave >> 1, wc = wave & 1;   // i-half, batch
    int l16  = lane & 15;
    int lq   = lane >> 4;
    int kq   = lq * 8;
    int b    = b0 + wc;

    f32x4 acc[8][4];
#pragma unroll
    for (int mt = 0; mt < 8; ++mt)
#pragma unroll
        for (int nt = 0; nt < 4; ++nt) acc[mt][nt] = (f32x4){0.f, 0.f, 0.f, 0.f};

    for (int jt = 0; jt < F / 32; ++jt) {
        // s1 fragment (broadcast): 8 bf16 -> f32
        short8 sv = *(const short8*)(s1L + wc * F + jt * 32 + kq);
        float sf[8];
#pragma unroll
        for (int e = 0; e < 8; ++e) sf[e] = bf2f(sv[e]);

        // B fragments: q2K row d scaled by s1, packed bf16 in registers
        short8 bfr[4];
#pragma unroll
        for (int nt = 0; nt < 4; ++nt) {
            int d = nt * 16 + l16;
            short8 qv = *(const short8*)(q2K + (jt * D + d) * 32 + kq);
            int4 packed;
            packed.x = pk_bf16(bf2f(qv[0]) * sf[0], bf2f(qv[1]) * sf[1]);
            packed.y = pk_bf16(bf2f(qv[2]) * sf[2], bf2f(qv[3]) * sf[3]);
            packed.z = pk_bf16(bf2f(qv[4]) * sf[4], bf2f(qv[5]) * sf[5]);
            packed.w = pk_bf16(bf2f(qv[6]) * sf[6], bf2f(qv[7]) * sf[7]);
            bfr[nt] = __builtin_bit_cast(short8, packed);
        }
        // A fragments + MFMA, 128 i-rows per wave
#pragma unroll
        for (int mt = 0; mt < 8; ++mt) {
            int i = wr * 128 + mt * 16 + l16;
            short8 af = *(const short8*)(At + ((size_t)jt * F + i) * 32 + kq);
#pragma unroll
            for (int nt = 0; nt < 4; ++nt)
                acc[mt][nt] = __builtin_amdgcn_mfma_f32_16x16x32_bf16(
                    af, bfr[nt], acc[mt][nt], 0, 0, 0);
        }
    }

    // ---- epilogue ----
#pragma unroll
    for (int mt = 0; mt < 8; ++mt) {
#pragma unroll
        for (int r = 0; r < 4; ++r) {
            int i = wr * 128 + mt * 16 + lq * 4 + r;
            float gg = gL[wc * F + i];
            float* orow = out + ((size_t)(b * F + i)) * D;
#pragma unroll
            for (int nt = 0; nt < 4; ++nt)
                orow[nt * 16 + l16] = gg * acc[mt][nt][r];
        }
    }
}

extern "C" void kernel_launch(void* const* d_in, const int* in_sizes, int n_in,
                              void* d_out, int out_size, void* d_ws, size_t ws_size,
                              hipStream_t stream) {
    const float* feature   = (const float*)d_in[0];
    const float* indicator = (const float*)d_in[1];
    const float* W_qk      = (const float*)d_in[2];
    const float* W_qkv     = (const float*)d_in[3];
    float* out = (float*)d_out;

    float* ws    = (float*)d_ws;
    float* trans = ws;                    // 2*F*D f32
    float* qkv   = trans + 2 * F * D;     // 3*F*D f32
    short* At    = (short*)(qkv + 3 * F * D);  // F*F bf16 (K-tiled)
    short* q2K   = At + F * F;                 // (F/32)*D*32 bf16 (K-tiled)

    hipLaunchKernelGGL(precompute_trans, dim3((5 * F * D) / 256), dim3(256), 0,
                       stream, indicator, W_qk, W_qkv, trans, qkv);
    hipLaunchKernelGGL(compute_Mt, dim3(F), dim3(F), 0, stream, trans, qkv, At, q2K);
    hipLaunchKernelGGL(fused_main, dim3(B / 2), dim3(256), 0, stream,
                       feature, qkv, At, q2K, out);
}